// Round 10
// baseline (449.972 us; speedup 1.0000x reference)
//
#include <hip/hip_runtime.h>

#define D_MODEL 1024
#define D_STATE 16
#define D_CONV  4
#define D_INNER 2048
#define DT_RANK 64
#define BATCH   2
#define SEQLEN  2048
#define NTOK    (BATCH * SEQLEN)   // 4096
#define NCH     64                 // scan chunks
#define LC      (SEQLEN / NCH)     // 32 steps per chunk
#define XKS     8                  // x_proj split-K factor
#define XNC     96                 // dt_rank + 2*d_state
#define OKS     4                  // out_proj split-K factor

// FACTS (r2-r9): inputs f32; d_out read as f32; bf16 internal copies for MFMA;
// async global_load_lds staging verified correct (r9).

// ---------- bf16 helpers ----------
__device__ __forceinline__ float bf2f(unsigned short v) {
    union { unsigned int u; float f; } c; c.u = ((unsigned int)v) << 16; return c.f;
}
__device__ __forceinline__ unsigned short f2bf(float f) {
    union { unsigned int u; float f; } c; c.f = f;
    unsigned int r = c.u + 0x7FFF + ((c.u >> 16) & 1);   // RNE
    return (unsigned short)(r >> 16);
}

struct __align__(8) U16x4 { unsigned short x, y, z, w; };

__device__ __forceinline__ float ldF(const void* p, size_t idx, int isbf) {
    return isbf ? bf2f(((const unsigned short*)p)[idx]) : ((const float*)p)[idx];
}
__device__ __forceinline__ void ldF4(const void* p, size_t idx, int isbf, float* o) {
    if (isbf) {
        U16x4 q = *(const U16x4*)&((const unsigned short*)p)[idx];
        o[0] = bf2f(q.x); o[1] = bf2f(q.y); o[2] = bf2f(q.z); o[3] = bf2f(q.w);
    } else {
        float4 q = *(const float4*)&((const float*)p)[idx];
        o[0] = q.x; o[1] = q.y; o[2] = q.z; o[3] = q.w;
    }
}
__device__ __forceinline__ void ld16f(const float* p, float* o) {
#pragma unroll
    for (int q = 0; q < 4; q++) {
        float4 v = *(const float4*)(p + 4 * q);
        o[4 * q + 0] = v.x; o[4 * q + 1] = v.y; o[4 * q + 2] = v.z; o[4 * q + 3] = v.w;
    }
}

// ---------------------------------------------------------------------------
__global__ void sniff(const unsigned int* __restrict__ Dw, int* __restrict__ flag) {
    if (threadIdx.x == 0) *flag = (Dw[0] == 0x3F803F80u) ? 1 : 0;
}

__launch_bounds__(256)
__global__ void cvt_bf16(const void* __restrict__ in, unsigned short* __restrict__ out,
                         int n, const int* __restrict__ flagp)
{
    const int isbf = *flagp;
    const int idx = blockIdx.x * 256 + threadIdx.x;
    if (idx < n) out[idx] = isbf ? ((const unsigned short*)in)[idx]
                                 : f2bf(((const float*)in)[idx]);
}

typedef __attribute__((ext_vector_type(8))) __bf16 bf16x8;
typedef __attribute__((ext_vector_type(4))) float  f32x4;

// ---------------------------------------------------------------------------
// MFMA layout probe (r8-verified): dmap[lane*4+r] = row | col<<4 in loader coords.
// ---------------------------------------------------------------------------
__global__ void mfma_probe(int* __restrict__ dmap) {
    __shared__ alignas(16) unsigned short As[16 * 32];
    __shared__ alignas(16) unsigned short Bs[16 * 32];
    const int t = threadIdx.x;           // 64 threads, one wave
    const int q = t >> 4, l15 = t & 15;

    for (int idx = t; idx < 512; idx += 64) {
        As[idx] = f2bf((float)(idx >> 5));
        Bs[idx] = f2bf(0.03125f);
    }
    __syncthreads();
    bf16x8 a1 = *(const bf16x8*)&As[l15 * 32 + q * 8];
    bf16x8 b1 = *(const bf16x8*)&Bs[l15 * 32 + q * 8];
    f32x4 acc1 = {0.f, 0.f, 0.f, 0.f};
    acc1 = __builtin_amdgcn_mfma_f32_16x16x32_bf16(a1, b1, acc1, 0, 0, 0);
    __syncthreads();

    for (int idx = t; idx < 512; idx += 64) {
        As[idx] = f2bf(0.03125f);
        Bs[idx] = f2bf((float)(idx >> 5));
    }
    __syncthreads();
    bf16x8 a2 = *(const bf16x8*)&As[l15 * 32 + q * 8];
    bf16x8 b2 = *(const bf16x8*)&Bs[l15 * 32 + q * 8];
    f32x4 acc2 = {0.f, 0.f, 0.f, 0.f};
    acc2 = __builtin_amdgcn_mfma_f32_16x16x32_bf16(a2, b2, acc2, 0, 0, 0);

#pragma unroll
    for (int r = 0; r < 4; r++) {
        int ma = (int)(acc1[r] + 0.5f);
        int nb = (int)(acc2[r] + 0.5f);
        if (ma < 0 || ma > 15 || nb < 0 || nb > 15) { ma = q * 4 + r; nb = l15; }
        dmap[t * 4 + r] = ma | (nb << 4);
    }
}

// ---------------------------------------------------------------------------
// MFMA bf16 GEMM, m97 async staging, generalized split-K:
// block z covers K range [z*Kc, (z+1)*Kc); writes C + z*M*N.
// For full-K call: gridDim.z=1, Kc=K.
// ---------------------------------------------------------------------------
__device__ __forceinline__ void gl2lds16(const void* g, void* l) {
    __builtin_amdgcn_global_load_lds(
        (const __attribute__((address_space(1))) unsigned int*)g,
        (__attribute__((address_space(3))) unsigned int*)l,
        16, 0, 0);
}

__launch_bounds__(256)
__global__ void gemm_mfma_bt(const unsigned short* __restrict__ A,
                             const unsigned short* __restrict__ B,
                             float* __restrict__ C,
                             int M, int N, int K, int Kc,
                             const int* __restrict__ dmap)
{
    __shared__ alignas(16) unsigned short As[128 * 32];
    __shared__ alignas(16) unsigned short Bs[128 * 32];
    const int t    = threadIdx.x;
    const int lane = t & 63;
    const int w    = t >> 6;
    const int m0   = blockIdx.y * 128, n0 = blockIdx.x * 128;
    const int wm   = (w >> 1) * 64,    wn = (w & 1) * 64;
    const int q    = lane >> 4, l15 = lane & 15;
    const int koff = blockIdx.z * Kc;

    int mp[4];
#pragma unroll
    for (int r = 0; r < 4; r++) mp[r] = dmap[lane * 4 + r];

    const int srow = t >> 2;          // 0..63
    const int skk  = (t & 3) * 8;     // shorts: 0,8,16,24

    f32x4 acc[4][4];
#pragma unroll
    for (int i = 0; i < 4; i++)
#pragma unroll
        for (int j = 0; j < 4; j++) acc[i][j] = (f32x4){0.f, 0.f, 0.f, 0.f};

    for (int k0 = koff; k0 < koff + Kc; k0 += 32) {
        __syncthreads();   // waves done reading LDS from previous iter
        gl2lds16(&A[(size_t)(m0 +      srow) * K + k0 + skk], &As[(     srow) * 32 + skk]);
        gl2lds16(&A[(size_t)(m0 + 64 + srow) * K + k0 + skk], &As[(64 + srow) * 32 + skk]);
        gl2lds16(&B[(size_t)(n0 +      srow) * K + k0 + skk], &Bs[(     srow) * 32 + skk]);
        gl2lds16(&B[(size_t)(n0 + 64 + srow) * K + k0 + skk], &Bs[(64 + srow) * 32 + skk]);
        __syncthreads();   // vmcnt(0) drained before barrier -> tiles visible

        bf16x8 af[4], bfr[4];
#pragma unroll
        for (int i = 0; i < 4; i++)
            af[i] = *(const bf16x8*)&As[(wm + i * 16 + l15) * 32 + q * 8];
#pragma unroll
        for (int j = 0; j < 4; j++)
            bfr[j] = *(const bf16x8*)&Bs[(wn + j * 16 + l15) * 32 + q * 8];
#pragma unroll
        for (int i = 0; i < 4; i++)
#pragma unroll
            for (int j = 0; j < 4; j++)
                acc[i][j] = __builtin_amdgcn_mfma_f32_16x16x32_bf16(
                    af[i], bfr[j], acc[i][j], 0, 0, 0);
    }

    float* out = C + (size_t)blockIdx.z * M * N;
#pragma unroll
    for (int i = 0; i < 4; i++) {
#pragma unroll
        for (int r = 0; r < 4; r++) {
            const int mo = mp[r] & 15, no = mp[r] >> 4;
            const int m = m0 + wm + i * 16 + mo;
#pragma unroll
            for (int j = 0; j < 4; j++) {
                const int n = n0 + wn + j * 16 + no;
                out[(size_t)m * N + n] = acc[i][j][r];
            }
        }
    }
}

// out_proj partial reduce: d_out = sum_z P[z]
__launch_bounds__(256)
__global__ void out_reduce(const float* __restrict__ part, float* __restrict__ out)
{
    const int idx = blockIdx.x * 256 + threadIdx.x;          // NTOK*D_MODEL
    float s = 0.f;
#pragma unroll
    for (int z = 0; z < OKS; z++) s += part[(size_t)z * NTOK * D_MODEL + idx];
    out[idx] = s;
}

// ---------------------------------------------------------------------------
// Small tiled fp32 GEMM (dt_proj): C = A @ B^T
// ---------------------------------------------------------------------------
template<int A_FLG, int C_FLG, int EPI>
__launch_bounds__(256)
__global__ void gemm_bt(const void* __restrict__ Av, int lda,
                        const void* __restrict__ Bv, int ldb,
                        void* __restrict__ Cv, int ldc,
                        int M, int N, int K,
                        const void* __restrict__ bias,
                        const int* __restrict__ flagp)
{
    const int isbf = *flagp;
    __shared__ alignas(16) float As[16][68];
    __shared__ alignas(16) float Bs[16][68];
    const int t  = threadIdx.x;
    const int m0 = blockIdx.y * 64, n0 = blockIdx.x * 64;
    const int lr = t >> 2;
    const int lk = (t & 3) * 4;
    const int tm = t >> 4, tn = t & 15;

    float acc[4][4];
#pragma unroll
    for (int i = 0; i < 4; i++)
#pragma unroll
        for (int j = 0; j < 4; j++) acc[i][j] = 0.f;

    for (int k0 = 0; k0 < K; k0 += 16) {
        float av[4], bv[4];
        {
            const int m = m0 + lr;
            if (A_FLG) ldF4(Av, (size_t)m * lda + k0 + lk, isbf, av);
            else {
                float4 p = *(const float4*)&((const float*)Av)[(size_t)m * lda + k0 + lk];
                av[0] = p.x; av[1] = p.y; av[2] = p.z; av[3] = p.w;
            }
        }
        {
            const int n = n0 + lr;
            if (n < N) ldF4(Bv, (size_t)n * ldb + k0 + lk, isbf, bv);
            else { bv[0] = bv[1] = bv[2] = bv[3] = 0.f; }
        }
        __syncthreads();
#pragma unroll
        for (int i = 0; i < 4; i++) { As[lk + i][lr] = av[i]; Bs[lk + i][lr] = bv[i]; }
        __syncthreads();

#pragma unroll
        for (int kk = 0; kk < 16; kk++) {
            float4 a = *(const float4*)&As[kk][tm * 4];
            float4 b = *(const float4*)&Bs[kk][tn * 4];
            float aa[4] = { a.x, a.y, a.z, a.w };
            float bb[4] = { b.x, b.y, b.z, b.w };
#pragma unroll
            for (int i = 0; i < 4; i++)
#pragma unroll
                for (int j = 0; j < 4; j++) acc[i][j] = fmaf(aa[i], bb[j], acc[i][j]);
        }
    }

#pragma unroll
    for (int i = 0; i < 4; i++) {
        const int m = m0 + tm * 4 + i;
#pragma unroll
        for (int j = 0; j < 4; j++) {
            const int n = n0 + tn * 4 + j;
            if (n < N) {
                float v = acc[i][j];
                if (EPI == 1) {
                    v += ldF(bias, n, isbf);
                    v = fmaxf(v, 0.f) + log1pf(expf(-fabsf(v)));
                }
                if (C_FLG && isbf) ((unsigned short*)Cv)[(size_t)m * ldc + n] = f2bf(v);
                else               ((float*)Cv)[(size_t)m * ldc + n] = v;
            }
        }
    }
}

// ---------------------------------------------------------------------------
// x_proj split-K: part[z][M][96] = xl[:, zKc:(z+1)Kc] @ x_proj_w[:, zKc:]^T
// ---------------------------------------------------------------------------
__launch_bounds__(256)
__global__ void xproj_splitk(const float* __restrict__ A,   // xl [4096,2048]
                             const float* __restrict__ B,   // x_proj_w [96,2048]
                             float* __restrict__ part)      // [XKS,4096,96]
{
    __shared__ alignas(16) float As[16][68];
    __shared__ alignas(16) float Bs[16][68];
    const int t  = threadIdx.x;
    const int m0 = blockIdx.y * 64, n0 = blockIdx.x * 64;
    const int koff = blockIdx.z * (D_INNER / XKS);           // 256-wide K chunk
    const int lr = t >> 2;
    const int lk = (t & 3) * 4;
    const int tm = t >> 4, tn = t & 15;

    float acc[4][4];
#pragma unroll
    for (int i = 0; i < 4; i++)
#pragma unroll
        for (int j = 0; j < 4; j++) acc[i][j] = 0.f;

    for (int k0 = koff; k0 < koff + D_INNER / XKS; k0 += 16) {
        float av[4], bv[4];
        {
            const int m = m0 + lr;
            float4 p = *(const float4*)&A[(size_t)m * D_INNER + k0 + lk];
            av[0] = p.x; av[1] = p.y; av[2] = p.z; av[3] = p.w;
        }
        {
            const int n = n0 + lr;
            if (n < XNC) {
                float4 p = *(const float4*)&B[(size_t)n * D_INNER + k0 + lk];
                bv[0] = p.x; bv[1] = p.y; bv[2] = p.z; bv[3] = p.w;
            } else { bv[0] = bv[1] = bv[2] = bv[3] = 0.f; }
        }
        __syncthreads();
#pragma unroll
        for (int i = 0; i < 4; i++) { As[lk + i][lr] = av[i]; Bs[lk + i][lr] = bv[i]; }
        __syncthreads();

#pragma unroll
        for (int kk = 0; kk < 16; kk++) {
            float4 a = *(const float4*)&As[kk][tm * 4];
            float4 b = *(const float4*)&Bs[kk][tn * 4];
            float aa[4] = { a.x, a.y, a.z, a.w };
            float bb[4] = { b.x, b.y, b.z, b.w };
#pragma unroll
            for (int i = 0; i < 4; i++)
#pragma unroll
                for (int j = 0; j < 4; j++) acc[i][j] = fmaf(aa[i], bb[j], acc[i][j]);
        }
    }

    float* out = part + (size_t)blockIdx.z * NTOK * XNC;
#pragma unroll
    for (int i = 0; i < 4; i++) {
        const int m = m0 + tm * 4 + i;
#pragma unroll
        for (int j = 0; j < 4; j++) {
            const int n = n0 + tn * 4 + j;
            if (n < XNC) out[(size_t)m * XNC + n] = acc[i][j];
        }
    }
}

__launch_bounds__(256)
__global__ void xproj_reduce(const float* __restrict__ part, float* __restrict__ xdbl)
{
    const int idx = blockIdx.x * 256 + threadIdx.x;          // NTOK*XNC
    float s = 0.f;
#pragma unroll
    for (int z = 0; z < XKS; z++) s += part[(size_t)z * NTOK * XNC + idx];
    xdbl[idx] = s;
}

// ---------------------------------------------------------------------------
// Depthwise causal conv1d (d_conv=4) + SiLU.
// ---------------------------------------------------------------------------
__launch_bounds__(256)
__global__ void conv_silu(const float* __restrict__ xz,
                          const void* __restrict__ conv_w,
                          const void* __restrict__ conv_b,
                          float* __restrict__ xl,
                          const int* __restrict__ flagp)
{
    const int isbf = *flagp;
    const int idx = blockIdx.x * 256 + threadIdx.x;
    const int d   = idx & (D_INNER - 1);
    const int tok = idx >> 11;
    const int l   = tok & (SEQLEN - 1);

    float acc = ldF(conv_b, d, isbf);
#pragma unroll
    for (int j = 0; j < 4; j++) {
        const int ll = l - 3 + j;
        if (ll >= 0)
            acc = fmaf(xz[(size_t)(tok - 3 + j) * (2 * D_INNER) + d],
                       ldF(conv_w, d * 4 + j, isbf), acc);
    }
    xl[idx] = acc / (1.f + expf(-acc));
}

// ---------------------------------------------------------------------------
// Scan phase 1: per-chunk local scan (h0=0) -> S[b,c,n,d], sumD[b,c,d].
// ---------------------------------------------------------------------------
__launch_bounds__(256)
__global__ void scan_chunk(const float* __restrict__ dlt,
                           const float* __restrict__ xl,
                           const float* __restrict__ xdbl,
                           const void* __restrict__ A_log,
                           float* __restrict__ S,
                           float* __restrict__ sumD,
                           const int* __restrict__ flagp)
{
    const int isbf = *flagp;
    const int t  = threadIdx.x;
    const int dg = blockIdx.x & 7;
    const int c  = (blockIdx.x >> 3) & (NCH - 1);
    const int b  = blockIdx.x >> 9;
    const int d  = dg * 256 + t;

    float An[16], h[16];
#pragma unroll
    for (int n = 0; n < 16; n++) {
        An[n] = -expf(ldF(A_log, d * 16 + n, isbf));
        h[n] = 0.f;
    }
    float sd = 0.f;
    const size_t r0 = (size_t)b * SEQLEN + c * LC;

    for (int i = 0; i < LC; i++) {
        const size_t r = r0 + i;
        const float dv = dlt[r * D_INNER + d];
        const float uv = xl [r * D_INNER + d];
        float Bv[16];
        ld16f(&xdbl[r * 96 + 64], Bv);
        const float du = dv * uv;
#pragma unroll
        for (int n = 0; n < 16; n++)
            h[n] = fmaf(__expf(dv * An[n]), h[n], du * Bv[n]);
        sd += dv;
    }

    const size_t base = (((size_t)b * NCH + c) * 16) * D_INNER + d;
#pragma unroll
    for (int n = 0; n < 16; n++) S[base + (size_t)n * D_INNER] = h[n];
    sumD[((size_t)b * NCH + c) * D_INNER + d] = sd;
}

// ---------------------------------------------------------------------------
// Scan phase 2: combine chunk states; S rewritten with chunk-START state H0.
// ---------------------------------------------------------------------------
__launch_bounds__(256)
__global__ void scan_combine(float* __restrict__ S,
                             const float* __restrict__ sumD,
                             const void* __restrict__ A_log,
                             const int* __restrict__ flagp)
{
    const int isbf = *flagp;
    const int g = blockIdx.x * 256 + threadIdx.x;
    const int d = g & (D_INNER - 1);
    const int n = (g >> 11) & 15;
    const int b = g >> 15;
    const float An = -expf(ldF(A_log, d * 16 + n, isbf));

    float hs = 0.f;
    for (int c = 0; c < NCH; c++) {
        const size_t idx = (((size_t)b * NCH + c) * 16 + n) * D_INNER + d;
        const float Sc = S[idx];
        const float sd = sumD[((size_t)b * NCH + c) * D_INNER + d];
        S[idx] = hs;
        hs = fmaf(__expf(An * sd), hs, Sc);
    }
}

// ---------------------------------------------------------------------------
// Scan phase 3: seeded re-scan; y = sum_n h*C; D-skip + silu(z) gate -> bf16 yg.
// ---------------------------------------------------------------------------
__launch_bounds__(256)
__global__ void scan_apply(const float* __restrict__ dlt,
                           const float* __restrict__ xl,
                           const float* __restrict__ xdbl,
                           const float* __restrict__ xz,
                           const void* __restrict__ A_log,
                           const void* __restrict__ Dp,
                           const float* __restrict__ S,   // holds H0
                           unsigned short* __restrict__ yg,
                           const int* __restrict__ flagp)
{
    const int isbf = *flagp;
    const int t  = threadIdx.x;
    const int dg = blockIdx.x & 7;
    const int c  = (blockIdx.x >> 3) & (NCH - 1);
    const int b  = blockIdx.x >> 9;
    const int d  = dg * 256 + t;

    float An[16], h[16];
    const size_t base = (((size_t)b * NCH + c) * 16) * D_INNER + d;
#pragma unroll
    for (int n = 0; n < 16; n++) {
        An[n] = -expf(ldF(A_log, d * 16 + n, isbf));
        h[n] = S[base + (size_t)n * D_INNER];
    }
    const float Dd = ldF(Dp, d, isbf);
    const size_t r0 = (size_t)b * SEQLEN + c * LC;

    for (int i = 0; i < LC; i++) {
        const size_t r = r0 + i;
        const float dv = dlt[r * D_INNER + d];
        const float uv = xl [r * D_INNER + d];
        const float zv = xz [r * (2 * D_INNER) + D_INNER + d];
        float Bv[16], Cv[16];
        ld16f(&xdbl[r * 96 + 64], Bv);
        ld16f(&xdbl[r * 96 + 80], Cv);
        const float du = dv * uv;
        float s[16];
#pragma unroll
        for (int n = 0; n < 16; n++) {
            h[n] = fmaf(__expf(dv * An[n]), h[n], du * Bv[n]);
            s[n] = h[n] * Cv[n];
        }
#pragma unroll
        for (int n = 0; n < 8; n++) s[n] += s[n + 8];
#pragma unroll
        for (int n = 0; n < 4; n++) s[n] += s[n + 4];
        s[0] += s[2]; s[1] += s[3];
        const float yv = s[0] + s[1] + uv * Dd;
        yg[r * D_INNER + d] = f2bf(yv * (zv / (1.f + expf(-zv))));
    }
}

// ---------------------------------------------------------------------------
extern "C" void kernel_launch(void* const* d_in, const int* in_sizes, int n_in,
                              void* d_out, int out_size, void* d_ws, size_t ws_size,
                              hipStream_t stream)
{
    const void* hidden     = d_in[0]; // f32
    const void* in_proj_w  = d_in[1];
    const void* conv_w     = d_in[2];
    const void* conv_b     = d_in[3];
    const void* x_proj_w   = d_in[4];
    const void* dt_proj_w  = d_in[5];
    const void* dt_proj_b  = d_in[6];
    const void* A_log      = d_in[7];
    const void* Dp         = d_in[8];
    const void* out_proj_w = d_in[9];

    char* ws = (char*)d_ws;
    float*          xz   = (float*)(ws);                        // [4096,4096]  64 MB
    float*          xl   = (float*)(ws + 67108864ull);          // [4096,2048]  32 MB
    float*          xdbl = (float*)(ws + 100663296ull);         // [4096,96]   1.5 MB
    float*          dlt  = (float*)(ws + 102236160ull);         // [4096,2048]  32 MB (step 4)
    unsigned short* yg   = (unsigned short*)(ws + 135790592ull);// [4096,2048] bf16 16 MB
    unsigned short* opwB = (unsigned short*)(ws + 152567808ull);// out_proj_w bf16 4 MB
    int*            flag = (int*)  (ws + 169345024ull);
    float*          S    = (float*)(ws + 169345280ull);         // 16 MB
    float*          sumD = (float*)(ws + 186122496ull);         // 1 MB
    int*            dmap = (int*)  (ws + 187171072ull);         // 256 B probe LUT
    // transient occupants of the dlt region (dead before step 4 writes dlt):
    unsigned short* hidB  = (unsigned short*)(ws + 102236160ull);              // 8 MB
    unsigned short* ipwB  = (unsigned short*)(ws + 102236160ull + 8388608ull); // 8 MB
    float*          xpart = (float*)(ws + 102236160ull);        // [8,4096,96] 12.6 MB
    // transient occupant of the xz region (dead after scan_apply):
    float*          opart = (float*)(ws);                       // [OKS,4096,1024] 64 MB

    dim3 blk(256);

    sniff<<<dim3(1), dim3(64), 0, stream>>>((const unsigned int*)Dp, (int*)flag);
    mfma_probe<<<dim3(1), dim3(64), 0, stream>>>(dmap);

    // 0) f32 -> bf16 copies for MFMA operands
    cvt_bf16<<<dim3(NTOK * D_MODEL / 256), blk, 0, stream>>>(hidden, hidB, NTOK * D_MODEL, flag);
    cvt_bf16<<<dim3(2 * D_INNER * D_MODEL / 256), blk, 0, stream>>>(in_proj_w, ipwB, 2 * D_INNER * D_MODEL, flag);
    cvt_bf16<<<dim3(D_MODEL * D_INNER / 256), blk, 0, stream>>>(out_proj_w, opwB, D_MODEL * D_INNER, flag);

    // 1) xz = hidden @ in_proj_w^T   [4096,4096]  (bf16 MFMA, full-K)
    gemm_mfma_bt<<<dim3(32, 32, 1), blk, 0, stream>>>(
        hidB, ipwB, xz, NTOK, 2 * D_INNER, D_MODEL, D_MODEL, dmap);

    // 2) xl = silu(causal_conv1d(x) + conv_b)
    conv_silu<<<dim3(NTOK * D_INNER / 256), blk, 0, stream>>>(xz, conv_w, conv_b, xl, flag);

    // 3) xdbl = xl @ x_proj_w^T  via split-K
    xproj_splitk<<<dim3(2, 64, XKS), blk, 0, stream>>>(
        xl, (const float*)x_proj_w, xpart);
    xproj_reduce<<<dim3(NTOK * XNC / 256), blk, 0, stream>>>(xpart, xdbl);

    // 4) delta = softplus(dt @ dt_proj_w^T + dt_proj_b)
    gemm_bt<0, 0, 1><<<dim3(32, 64), blk, 0, stream>>>(
        xdbl, 96, dt_proj_w, DT_RANK, dlt, D_INNER,
        NTOK, D_INNER, DT_RANK, dt_proj_b, flag);

    // 5) chunked parallel scan + D-skip + silu(z) gate -> yg (bf16)
    scan_chunk<<<dim3(BATCH * NCH * (D_INNER / 256)), blk, 0, stream>>>(
        dlt, xl, xdbl, A_log, S, sumD, flag);
    scan_combine<<<dim3(BATCH * 16 * D_INNER / 256), blk, 0, stream>>>(
        S, sumD, A_log, flag);
    scan_apply<<<dim3(BATCH * NCH * (D_INNER / 256)), blk, 0, stream>>>(
        dlt, xl, xdbl, xz, A_log, Dp, S, yg, flag);

    // 6) out_proj via split-K=4 into opart (overlays dead xz), then reduce
    gemm_mfma_bt<<<dim3(8, 32, OKS), blk, 0, stream>>>(
        yg, opwB, opart, NTOK, D_MODEL, D_INNER, D_INNER / OKS, dmap);
    out_reduce<<<dim3(NTOK * D_MODEL / 256), blk, 0, stream>>>(opart, (float*)d_out);
}

// Round 12
// 407.267 us; speedup vs baseline: 1.1049x; 1.1049x over previous
//
#include <hip/hip_runtime.h>

#define D_MODEL 1024
#define D_STATE 16
#define D_CONV  4
#define D_INNER 2048
#define DT_RANK 64
#define BATCH   2
#define SEQLEN  2048
#define NTOK    (BATCH * SEQLEN)   // 4096
#define NCH     64                 // scan chunks
#define LC      (SEQLEN / NCH)     // 32 steps per chunk
#define XKS     8                  // x_proj split-K factor
#define XNC     96                 // dt_rank + 2*d_state

// FACTS (r2-r11): inputs f32; d_out read as f32; bf16 internal copies for MFMA;
// async global_load_lds verified (r9); out_proj split-K regressed (r10);
// ws_size is BETWEEN 187,171,328 and 187,957,760 bytes (r11 abort = OOB ws
// write when xdt/dtwB were appended past dmap) -> keep ALL buffers within the
// r8-proven 187,171,328-byte footprint. xdt/dtwB now live in the unused
// 12.6 MB hole between opwB(end=156,762,112) and flag(169,345,024).

// ---------- bf16 helpers ----------
__device__ __forceinline__ float bf2f(unsigned short v) {
    union { unsigned int u; float f; } c; c.u = ((unsigned int)v) << 16; return c.f;
}
__device__ __forceinline__ unsigned short f2bf(float f) {
    union { unsigned int u; float f; } c; c.f = f;
    unsigned int r = c.u + 0x7FFF + ((c.u >> 16) & 1);   // RNE
    return (unsigned short)(r >> 16);
}

struct __align__(8) U16x4 { unsigned short x, y, z, w; };

__device__ __forceinline__ float ldF(const void* p, size_t idx, int isbf) {
    return isbf ? bf2f(((const unsigned short*)p)[idx]) : ((const float*)p)[idx];
}
__device__ __forceinline__ void ld16f(const float* p, float* o) {
#pragma unroll
    for (int q = 0; q < 4; q++) {
        float4 v = *(const float4*)(p + 4 * q);
        o[4 * q + 0] = v.x; o[4 * q + 1] = v.y; o[4 * q + 2] = v.z; o[4 * q + 3] = v.w;
    }
}

// ---------------------------------------------------------------------------
__global__ void sniff(const unsigned int* __restrict__ Dw, int* __restrict__ flag) {
    if (threadIdx.x == 0) *flag = (Dw[0] == 0x3F803F80u) ? 1 : 0;
}

__launch_bounds__(256)
__global__ void cvt_bf16(const void* __restrict__ in, unsigned short* __restrict__ out,
                         int n, const int* __restrict__ flagp)
{
    const int isbf = *flagp;
    const int idx = blockIdx.x * 256 + threadIdx.x;
    if (idx < n) out[idx] = isbf ? ((const unsigned short*)in)[idx]
                                 : f2bf(((const float*)in)[idx]);
}

// pack xdbl[:, 0:64] (f32, our intermediate) -> bf16 [4096,64]
__launch_bounds__(256)
__global__ void pack_xdt(const float* __restrict__ xdbl, unsigned short* __restrict__ xdt)
{
    const int idx = blockIdx.x * 256 + threadIdx.x;   // NTOK*64
    const int m = idx >> 6, k = idx & 63;
    xdt[idx] = f2bf(xdbl[m * 96 + k]);
}

typedef __attribute__((ext_vector_type(8))) __bf16 bf16x8;
typedef __attribute__((ext_vector_type(4))) float  f32x4;

// ---------------------------------------------------------------------------
// MFMA layout probe (r8-verified): dmap[lane*4+r] = row | col<<4 in loader coords.
// ---------------------------------------------------------------------------
__global__ void mfma_probe(int* __restrict__ dmap) {
    __shared__ alignas(16) unsigned short As[16 * 32];
    __shared__ alignas(16) unsigned short Bs[16 * 32];
    const int t = threadIdx.x;           // 64 threads, one wave
    const int q = t >> 4, l15 = t & 15;

    for (int idx = t; idx < 512; idx += 64) {
        As[idx] = f2bf((float)(idx >> 5));
        Bs[idx] = f2bf(0.03125f);
    }
    __syncthreads();
    bf16x8 a1 = *(const bf16x8*)&As[l15 * 32 + q * 8];
    bf16x8 b1 = *(const bf16x8*)&Bs[l15 * 32 + q * 8];
    f32x4 acc1 = {0.f, 0.f, 0.f, 0.f};
    acc1 = __builtin_amdgcn_mfma_f32_16x16x32_bf16(a1, b1, acc1, 0, 0, 0);
    __syncthreads();

    for (int idx = t; idx < 512; idx += 64) {
        As[idx] = f2bf(0.03125f);
        Bs[idx] = f2bf((float)(idx >> 5));
    }
    __syncthreads();
    bf16x8 a2 = *(const bf16x8*)&As[l15 * 32 + q * 8];
    bf16x8 b2 = *(const bf16x8*)&Bs[l15 * 32 + q * 8];
    f32x4 acc2 = {0.f, 0.f, 0.f, 0.f};
    acc2 = __builtin_amdgcn_mfma_f32_16x16x32_bf16(a2, b2, acc2, 0, 0, 0);

#pragma unroll
    for (int r = 0; r < 4; r++) {
        int ma = (int)(acc1[r] + 0.5f);
        int nb = (int)(acc2[r] + 0.5f);
        if (ma < 0 || ma > 15 || nb < 0 || nb > 15) { ma = q * 4 + r; nb = l15; }
        dmap[t * 4 + r] = ma | (nb << 4);
    }
}

// ---------------------------------------------------------------------------
// MFMA bf16 GEMM, m97 async staging. EPI==1: v = softplus(v + bias[n]).
// ---------------------------------------------------------------------------
__device__ __forceinline__ void gl2lds16(const void* g, void* l) {
    __builtin_amdgcn_global_load_lds(
        (const __attribute__((address_space(1))) unsigned int*)g,
        (__attribute__((address_space(3))) unsigned int*)l,
        16, 0, 0);
}

template<int EPI>
__launch_bounds__(256)
__global__ void gemm_mfma_bt(const unsigned short* __restrict__ A,
                             const unsigned short* __restrict__ B,
                             float* __restrict__ C,
                             int M, int N, int K,
                             const int* __restrict__ dmap,
                             const void* __restrict__ bias,
                             const int* __restrict__ flagp)
{
    __shared__ alignas(16) unsigned short As[128 * 32];
    __shared__ alignas(16) unsigned short Bs[128 * 32];
    const int t    = threadIdx.x;
    const int lane = t & 63;
    const int w    = t >> 6;
    const int m0   = blockIdx.y * 128, n0 = blockIdx.x * 128;
    const int wm   = (w >> 1) * 64,    wn = (w & 1) * 64;
    const int q    = lane >> 4, l15 = lane & 15;

    int mp[4];
#pragma unroll
    for (int r = 0; r < 4; r++) mp[r] = dmap[lane * 4 + r];

    const int srow = t >> 2;          // 0..63
    const int skk  = (t & 3) * 8;     // shorts: 0,8,16,24

    f32x4 acc[4][4];
#pragma unroll
    for (int i = 0; i < 4; i++)
#pragma unroll
        for (int j = 0; j < 4; j++) acc[i][j] = (f32x4){0.f, 0.f, 0.f, 0.f};

    for (int k0 = 0; k0 < K; k0 += 32) {
        __syncthreads();   // waves done reading LDS from previous iter
        gl2lds16(&A[(size_t)(m0 +      srow) * K + k0 + skk], &As[(     srow) * 32 + skk]);
        gl2lds16(&A[(size_t)(m0 + 64 + srow) * K + k0 + skk], &As[(64 + srow) * 32 + skk]);
        gl2lds16(&B[(size_t)(n0 +      srow) * K + k0 + skk], &Bs[(     srow) * 32 + skk]);
        gl2lds16(&B[(size_t)(n0 + 64 + srow) * K + k0 + skk], &Bs[(64 + srow) * 32 + skk]);
        __syncthreads();   // vmcnt(0) drained before barrier -> tiles visible

        bf16x8 af[4], bfr[4];
#pragma unroll
        for (int i = 0; i < 4; i++)
            af[i] = *(const bf16x8*)&As[(wm + i * 16 + l15) * 32 + q * 8];
#pragma unroll
        for (int j = 0; j < 4; j++)
            bfr[j] = *(const bf16x8*)&Bs[(wn + j * 16 + l15) * 32 + q * 8];
#pragma unroll
        for (int i = 0; i < 4; i++)
#pragma unroll
            for (int j = 0; j < 4; j++)
                acc[i][j] = __builtin_amdgcn_mfma_f32_16x16x32_bf16(
                    af[i], bfr[j], acc[i][j], 0, 0, 0);
    }

    const int isbf = EPI ? *flagp : 0;
#pragma unroll
    for (int i = 0; i < 4; i++) {
#pragma unroll
        for (int r = 0; r < 4; r++) {
            const int mo = mp[r] & 15, no = mp[r] >> 4;
            const int m = m0 + wm + i * 16 + mo;
#pragma unroll
            for (int j = 0; j < 4; j++) {
                const int n = n0 + wn + j * 16 + no;
                float v = acc[i][j][r];
                if (EPI == 1) {   // softplus(v + bias[n]), fast-math
                    v += ldF(bias, n, isbf);
                    v = fmaxf(v, 0.f) + __logf(1.f + __expf(-fabsf(v)));
                }
                C[(size_t)m * N + n] = v;
            }
        }
    }
}

// ---------------------------------------------------------------------------
// x_proj split-K: part[z][M][96] = xl[:, zKc:(z+1)Kc] @ x_proj_w[:, zKc:]^T
// ---------------------------------------------------------------------------
__launch_bounds__(256)
__global__ void xproj_splitk(const float* __restrict__ A,   // xl [4096,2048]
                             const float* __restrict__ B,   // x_proj_w [96,2048]
                             float* __restrict__ part)      // [XKS,4096,96]
{
    __shared__ alignas(16) float As[16][68];
    __shared__ alignas(16) float Bs[16][68];
    const int t  = threadIdx.x;
    const int m0 = blockIdx.y * 64, n0 = blockIdx.x * 64;
    const int koff = blockIdx.z * (D_INNER / XKS);           // 256-wide K chunk
    const int lr = t >> 2;
    const int lk = (t & 3) * 4;
    const int tm = t >> 4, tn = t & 15;

    float acc[4][4];
#pragma unroll
    for (int i = 0; i < 4; i++)
#pragma unroll
        for (int j = 0; j < 4; j++) acc[i][j] = 0.f;

    for (int k0 = koff; k0 < koff + D_INNER / XKS; k0 += 16) {
        float av[4], bv[4];
        {
            const int m = m0 + lr;
            float4 p = *(const float4*)&A[(size_t)m * D_INNER + k0 + lk];
            av[0] = p.x; av[1] = p.y; av[2] = p.z; av[3] = p.w;
        }
        {
            const int n = n0 + lr;
            if (n < XNC) {
                float4 p = *(const float4*)&B[(size_t)n * D_INNER + k0 + lk];
                bv[0] = p.x; bv[1] = p.y; bv[2] = p.z; bv[3] = p.w;
            } else { bv[0] = bv[1] = bv[2] = bv[3] = 0.f; }
        }
        __syncthreads();
#pragma unroll
        for (int i = 0; i < 4; i++) { As[lk + i][lr] = av[i]; Bs[lk + i][lr] = bv[i]; }
        __syncthreads();

#pragma unroll
        for (int kk = 0; kk < 16; kk++) {
            float4 a = *(const float4*)&As[kk][tm * 4];
            float4 b = *(const float4*)&Bs[kk][tn * 4];
            float aa[4] = { a.x, a.y, a.z, a.w };
            float bb[4] = { b.x, b.y, b.z, b.w };
#pragma unroll
            for (int i = 0; i < 4; i++)
#pragma unroll
                for (int j = 0; j < 4; j++) acc[i][j] = fmaf(aa[i], bb[j], acc[i][j]);
        }
    }

    float* out = part + (size_t)blockIdx.z * NTOK * XNC;
#pragma unroll
    for (int i = 0; i < 4; i++) {
        const int m = m0 + tm * 4 + i;
#pragma unroll
        for (int j = 0; j < 4; j++) {
            const int n = n0 + tn * 4 + j;
            if (n < XNC) out[(size_t)m * XNC + n] = acc[i][j];
        }
    }
}

__launch_bounds__(256)
__global__ void xproj_reduce(const float* __restrict__ part, float* __restrict__ xdbl)
{
    const int idx = blockIdx.x * 256 + threadIdx.x;          // NTOK*XNC
    float s = 0.f;
#pragma unroll
    for (int z = 0; z < XKS; z++) s += part[(size_t)z * NTOK * XNC + idx];
    xdbl[idx] = s;
}

// ---------------------------------------------------------------------------
// Depthwise causal conv1d (d_conv=4) + SiLU.
// ---------------------------------------------------------------------------
__launch_bounds__(256)
__global__ void conv_silu(const float* __restrict__ xz,
                          const void* __restrict__ conv_w,
                          const void* __restrict__ conv_b,
                          float* __restrict__ xl,
                          const int* __restrict__ flagp)
{
    const int isbf = *flagp;
    const int idx = blockIdx.x * 256 + threadIdx.x;
    const int d   = idx & (D_INNER - 1);
    const int tok = idx >> 11;
    const int l   = tok & (SEQLEN - 1);

    float acc = ldF(conv_b, d, isbf);
#pragma unroll
    for (int j = 0; j < 4; j++) {
        const int ll = l - 3 + j;
        if (ll >= 0)
            acc = fmaf(xz[(size_t)(tok - 3 + j) * (2 * D_INNER) + d],
                       ldF(conv_w, d * 4 + j, isbf), acc);
    }
    xl[idx] = acc / (1.f + expf(-acc));
}

// ---------------------------------------------------------------------------
// Scan phase 1: per-chunk local scan (h0=0) -> S[b,c,n,d], sumD[b,c,d].
// ---------------------------------------------------------------------------
__launch_bounds__(256)
__global__ void scan_chunk(const float* __restrict__ dlt,
                           const float* __restrict__ xl,
                           const float* __restrict__ xdbl,
                           const void* __restrict__ A_log,
                           float* __restrict__ S,
                           float* __restrict__ sumD,
                           const int* __restrict__ flagp)
{
    const int isbf = *flagp;
    const int t  = threadIdx.x;
    const int dg = blockIdx.x & 7;
    const int c  = (blockIdx.x >> 3) & (NCH - 1);
    const int b  = blockIdx.x >> 9;
    const int d  = dg * 256 + t;

    float An[16], h[16];
#pragma unroll
    for (int n = 0; n < 16; n++) {
        An[n] = -expf(ldF(A_log, d * 16 + n, isbf));
        h[n] = 0.f;
    }
    float sd = 0.f;
    const size_t r0 = (size_t)b * SEQLEN + c * LC;

    for (int i = 0; i < LC; i++) {
        const size_t r = r0 + i;
        const float dv = dlt[r * D_INNER + d];
        const float uv = xl [r * D_INNER + d];
        float Bv[16];
        ld16f(&xdbl[r * 96 + 64], Bv);
        const float du = dv * uv;
#pragma unroll
        for (int n = 0; n < 16; n++)
            h[n] = fmaf(__expf(dv * An[n]), h[n], du * Bv[n]);
        sd += dv;
    }

    const size_t base = (((size_t)b * NCH + c) * 16) * D_INNER + d;
#pragma unroll
    for (int n = 0; n < 16; n++) S[base + (size_t)n * D_INNER] = h[n];
    sumD[((size_t)b * NCH + c) * D_INNER + d] = sd;
}

// ---------------------------------------------------------------------------
// Scan phase 2: combine chunk states; S rewritten with chunk-START state H0.
// ---------------------------------------------------------------------------
__launch_bounds__(256)
__global__ void scan_combine(float* __restrict__ S,
                             const float* __restrict__ sumD,
                             const void* __restrict__ A_log,
                             const int* __restrict__ flagp)
{
    const int isbf = *flagp;
    const int g = blockIdx.x * 256 + threadIdx.x;
    const int d = g & (D_INNER - 1);
    const int n = (g >> 11) & 15;
    const int b = g >> 15;
    const float An = -expf(ldF(A_log, d * 16 + n, isbf));

    float hs = 0.f;
    for (int c = 0; c < NCH; c++) {
        const size_t idx = (((size_t)b * NCH + c) * 16 + n) * D_INNER + d;
        const float Sc = S[idx];
        const float sd = sumD[((size_t)b * NCH + c) * D_INNER + d];
        S[idx] = hs;
        hs = fmaf(__expf(An * sd), hs, Sc);
    }
}

// ---------------------------------------------------------------------------
// Scan phase 3: seeded re-scan; y = sum_n h*C; D-skip + silu(z) gate -> bf16 yg.
// ---------------------------------------------------------------------------
__launch_bounds__(256)
__global__ void scan_apply(const float* __restrict__ dlt,
                           const float* __restrict__ xl,
                           const float* __restrict__ xdbl,
                           const float* __restrict__ xz,
                           const void* __restrict__ A_log,
                           const void* __restrict__ Dp,
                           const float* __restrict__ S,   // holds H0
                           unsigned short* __restrict__ yg,
                           const int* __restrict__ flagp)
{
    const int isbf = *flagp;
    const int t  = threadIdx.x;
    const int dg = blockIdx.x & 7;
    const int c  = (blockIdx.x >> 3) & (NCH - 1);
    const int b  = blockIdx.x >> 9;
    const int d  = dg * 256 + t;

    float An[16], h[16];
    const size_t base = (((size_t)b * NCH + c) * 16) * D_INNER + d;
#pragma unroll
    for (int n = 0; n < 16; n++) {
        An[n] = -expf(ldF(A_log, d * 16 + n, isbf));
        h[n] = S[base + (size_t)n * D_INNER];
    }
    const float Dd = ldF(Dp, d, isbf);
    const size_t r0 = (size_t)b * SEQLEN + c * LC;

    for (int i = 0; i < LC; i++) {
        const size_t r = r0 + i;
        const float dv = dlt[r * D_INNER + d];
        const float uv = xl [r * D_INNER + d];
        const float zv = xz [r * (2 * D_INNER) + D_INNER + d];
        float Bv[16], Cv[16];
        ld16f(&xdbl[r * 96 + 64], Bv);
        ld16f(&xdbl[r * 96 + 80], Cv);
        const float du = dv * uv;
        float s[16];
#pragma unroll
        for (int n = 0; n < 16; n++) {
            h[n] = fmaf(__expf(dv * An[n]), h[n], du * Bv[n]);
            s[n] = h[n] * Cv[n];
        }
#pragma unroll
        for (int n = 0; n < 8; n++) s[n] += s[n + 8];
#pragma unroll
        for (int n = 0; n < 4; n++) s[n] += s[n + 4];
        s[0] += s[2]; s[1] += s[3];
        const float yv = s[0] + s[1] + uv * Dd;
        yg[r * D_INNER + d] = f2bf(yv * (zv / (1.f + expf(-zv))));
    }
}

// ---------------------------------------------------------------------------
extern "C" void kernel_launch(void* const* d_in, const int* in_sizes, int n_in,
                              void* d_out, int out_size, void* d_ws, size_t ws_size,
                              hipStream_t stream)
{
    const void* hidden     = d_in[0]; // f32
    const void* in_proj_w  = d_in[1];
    const void* conv_w     = d_in[2];
    const void* conv_b     = d_in[3];
    const void* x_proj_w   = d_in[4];
    const void* dt_proj_w  = d_in[5];
    const void* dt_proj_b  = d_in[6];
    const void* A_log      = d_in[7];
    const void* Dp         = d_in[8];
    const void* out_proj_w = d_in[9];

    char* ws = (char*)d_ws;
    float*          xz   = (float*)(ws);                        // [4096,4096]  64 MB
    float*          xl   = (float*)(ws + 67108864ull);          // [4096,2048]  32 MB
    float*          xdbl = (float*)(ws + 100663296ull);         // [4096,96]   1.5 MB
    float*          dlt  = (float*)(ws + 102236160ull);         // [4096,2048]  32 MB (step 4)
    unsigned short* yg   = (unsigned short*)(ws + 135790592ull);// [4096,2048] bf16 16 MB
    unsigned short* opwB = (unsigned short*)(ws + 152567808ull);// out_proj_w bf16 4 MB
    unsigned short* xdt  = (unsigned short*)(ws + 156762112ull);// [4096,64] bf16 512 KB (hole)
    unsigned short* dtwB = (unsigned short*)(ws + 157286400ull);// [2048,64] bf16 256 KB (hole)
    int*            flag = (int*)  (ws + 169345024ull);
    float*          S    = (float*)(ws + 169345280ull);         // 16 MB
    float*          sumD = (float*)(ws + 186122496ull);         // 1 MB
    int*            dmap = (int*)  (ws + 187171072ull);         // 256 B probe LUT
    // transient occupants of the dlt region (dead before dt-GEMM writes dlt):
    unsigned short* hidB  = (unsigned short*)(ws + 102236160ull);              // 8 MB
    unsigned short* ipwB  = (unsigned short*)(ws + 102236160ull + 8388608ull); // 8 MB
    float*          xpart = (float*)(ws + 102236160ull);        // [8,4096,96] 12.6 MB

    dim3 blk(256);

    sniff<<<dim3(1), dim3(64), 0, stream>>>((const unsigned int*)Dp, (int*)flag);
    mfma_probe<<<dim3(1), dim3(64), 0, stream>>>(dmap);

    // 0) f32 -> bf16 copies for MFMA operands
    cvt_bf16<<<dim3(NTOK * D_MODEL / 256), blk, 0, stream>>>(hidden, hidB, NTOK * D_MODEL, flag);
    cvt_bf16<<<dim3(2 * D_INNER * D_MODEL / 256), blk, 0, stream>>>(in_proj_w, ipwB, 2 * D_INNER * D_MODEL, flag);
    cvt_bf16<<<dim3(D_MODEL * D_INNER / 256), blk, 0, stream>>>(out_proj_w, opwB, D_MODEL * D_INNER, flag);
    cvt_bf16<<<dim3(D_INNER * DT_RANK / 256), blk, 0, stream>>>(dt_proj_w, dtwB, D_INNER * DT_RANK, flag);

    // 1) xz = hidden @ in_proj_w^T   [4096,4096]  (bf16 MFMA)
    gemm_mfma_bt<0><<<dim3(32, 32), blk, 0, stream>>>(
        hidB, ipwB, xz, NTOK, 2 * D_INNER, D_MODEL, dmap, nullptr, flag);

    // 2) xl = silu(causal_conv1d(x) + conv_b)
    conv_silu<<<dim3(NTOK * D_INNER / 256), blk, 0, stream>>>(xz, conv_w, conv_b, xl, flag);

    // 3) xdbl = xl @ x_proj_w^T  via split-K
    xproj_splitk<<<dim3(2, 64, XKS), blk, 0, stream>>>(
        xl, (const float*)x_proj_w, xpart);
    xproj_reduce<<<dim3(NTOK * XNC / 256), blk, 0, stream>>>(xpart, xdbl);

    // 4) delta = softplus(dt @ dt_proj_w^T + dt_proj_b)  via bf16 MFMA (K=64)
    pack_xdt<<<dim3(NTOK * DT_RANK / 256), blk, 0, stream>>>(xdbl, xdt);
    gemm_mfma_bt<1><<<dim3(16, 32), blk, 0, stream>>>(
        xdt, dtwB, dlt, NTOK, D_INNER, DT_RANK, dmap, dt_proj_b, flag);

    // 5) chunked parallel scan + D-skip + silu(z) gate -> yg (bf16)
    scan_chunk<<<dim3(BATCH * NCH * (D_INNER / 256)), blk, 0, stream>>>(
        dlt, xl, xdbl, A_log, S, sumD, flag);
    scan_combine<<<dim3(BATCH * 16 * D_INNER / 256), blk, 0, stream>>>(
        S, sumD, A_log, flag);
    scan_apply<<<dim3(BATCH * NCH * (D_INNER / 256)), blk, 0, stream>>>(
        dlt, xl, xdbl, xz, A_log, Dp, S, yg, flag);

    // 6) out = yg @ out_proj_w^T -> f32 d_out   (bf16 MFMA, full-K)
    gemm_mfma_bt<0><<<dim3(8, 32), blk, 0, stream>>>(
        yg, opwB, (float*)d_out, NTOK, D_MODEL, D_INNER, dmap, nullptr, flag);
}

// Round 13
// 398.091 us; speedup vs baseline: 1.1303x; 1.0231x over previous
//
#include <hip/hip_runtime.h>

#define D_MODEL 1024
#define D_STATE 16
#define D_CONV  4
#define D_INNER 2048
#define DT_RANK 64
#define BATCH   2
#define SEQLEN  2048
#define NTOK    (BATCH * SEQLEN)   // 4096
#define NCH     64                 // scan chunks
#define LC      (SEQLEN / NCH)     // 32 steps per chunk
#define XKS     8                  // x_proj split-K factor
#define XNC     96                 // dt_rank + 2*d_state

// FACTS (r2-r12): inputs f32; d_out read as f32; bf16 internal copies for MFMA;
// async global_load_lds verified (r9); out_proj split-K regressed (r10 — partial
// traffic > latency win); ws peak must stay <= 187,171,328 B (r11 abort);
// dt_proj MFMA verified (r12). r13: out_proj gets BN=64 tile (2 blocks/CU) +
// M-major grid (XCD pins A-tiles in L2; small B streams).

// ---------- bf16 helpers ----------
__device__ __forceinline__ float bf2f(unsigned short v) {
    union { unsigned int u; float f; } c; c.u = ((unsigned int)v) << 16; return c.f;
}
__device__ __forceinline__ unsigned short f2bf(float f) {
    union { unsigned int u; float f; } c; c.f = f;
    unsigned int r = c.u + 0x7FFF + ((c.u >> 16) & 1);   // RNE
    return (unsigned short)(r >> 16);
}

struct __align__(8) U16x4 { unsigned short x, y, z, w; };

__device__ __forceinline__ float ldF(const void* p, size_t idx, int isbf) {
    return isbf ? bf2f(((const unsigned short*)p)[idx]) : ((const float*)p)[idx];
}
__device__ __forceinline__ void ld16f(const float* p, float* o) {
#pragma unroll
    for (int q = 0; q < 4; q++) {
        float4 v = *(const float4*)(p + 4 * q);
        o[4 * q + 0] = v.x; o[4 * q + 1] = v.y; o[4 * q + 2] = v.z; o[4 * q + 3] = v.w;
    }
}

// ---------------------------------------------------------------------------
__global__ void sniff(const unsigned int* __restrict__ Dw, int* __restrict__ flag) {
    if (threadIdx.x == 0) *flag = (Dw[0] == 0x3F803F80u) ? 1 : 0;
}

__launch_bounds__(256)
__global__ void cvt_bf16(const void* __restrict__ in, unsigned short* __restrict__ out,
                         int n, const int* __restrict__ flagp)
{
    const int isbf = *flagp;
    const int idx = blockIdx.x * 256 + threadIdx.x;
    if (idx < n) out[idx] = isbf ? ((const unsigned short*)in)[idx]
                                 : f2bf(((const float*)in)[idx]);
}

// pack xdbl[:, 0:64] (f32) -> bf16 [4096,64]
__launch_bounds__(256)
__global__ void pack_xdt(const float* __restrict__ xdbl, unsigned short* __restrict__ xdt)
{
    const int idx = blockIdx.x * 256 + threadIdx.x;   // NTOK*64
    const int m = idx >> 6, k = idx & 63;
    xdt[idx] = f2bf(xdbl[m * 96 + k]);
}

typedef __attribute__((ext_vector_type(8))) __bf16 bf16x8;
typedef __attribute__((ext_vector_type(4))) float  f32x4;

// ---------------------------------------------------------------------------
// MFMA layout probe (r8-verified): dmap[lane*4+r] = row | col<<4 in loader coords.
// ---------------------------------------------------------------------------
__global__ void mfma_probe(int* __restrict__ dmap) {
    __shared__ alignas(16) unsigned short As[16 * 32];
    __shared__ alignas(16) unsigned short Bs[16 * 32];
    const int t = threadIdx.x;           // 64 threads, one wave
    const int q = t >> 4, l15 = t & 15;

    for (int idx = t; idx < 512; idx += 64) {
        As[idx] = f2bf((float)(idx >> 5));
        Bs[idx] = f2bf(0.03125f);
    }
    __syncthreads();
    bf16x8 a1 = *(const bf16x8*)&As[l15 * 32 + q * 8];
    bf16x8 b1 = *(const bf16x8*)&Bs[l15 * 32 + q * 8];
    f32x4 acc1 = {0.f, 0.f, 0.f, 0.f};
    acc1 = __builtin_amdgcn_mfma_f32_16x16x32_bf16(a1, b1, acc1, 0, 0, 0);
    __syncthreads();

    for (int idx = t; idx < 512; idx += 64) {
        As[idx] = f2bf(0.03125f);
        Bs[idx] = f2bf((float)(idx >> 5));
    }
    __syncthreads();
    bf16x8 a2 = *(const bf16x8*)&As[l15 * 32 + q * 8];
    bf16x8 b2 = *(const bf16x8*)&Bs[l15 * 32 + q * 8];
    f32x4 acc2 = {0.f, 0.f, 0.f, 0.f};
    acc2 = __builtin_amdgcn_mfma_f32_16x16x32_bf16(a2, b2, acc2, 0, 0, 0);

#pragma unroll
    for (int r = 0; r < 4; r++) {
        int ma = (int)(acc1[r] + 0.5f);
        int nb = (int)(acc2[r] + 0.5f);
        if (ma < 0 || ma > 15 || nb < 0 || nb > 15) { ma = q * 4 + r; nb = l15; }
        dmap[t * 4 + r] = ma | (nb << 4);
    }
}

// ---------------------------------------------------------------------------
// MFMA bf16 GEMM, m97 async staging.
// NJ: n-frags per wave (4 -> BN=128 2x2 waves of 64x64; 2 -> BN=64 waves 64x32).
// SWAP: blockIdx.x indexes M-tiles (XCD L2 pinning for A). EPI==1: softplus+bias.
// ---------------------------------------------------------------------------
__device__ __forceinline__ void gl2lds16(const void* g, void* l) {
    __builtin_amdgcn_global_load_lds(
        (const __attribute__((address_space(1))) unsigned int*)g,
        (__attribute__((address_space(3))) unsigned int*)l,
        16, 0, 0);
}

template<int EPI, int NJ, int SWAP>
__launch_bounds__(256)
__global__ void gemm_mfma_bt(const unsigned short* __restrict__ A,
                             const unsigned short* __restrict__ B,
                             float* __restrict__ C,
                             int M, int N, int K,
                             const int* __restrict__ dmap,
                             const void* __restrict__ bias,
                             const int* __restrict__ flagp)
{
    constexpr int BN = NJ * 32;
    __shared__ alignas(16) unsigned short As[128 * 32];
    __shared__ alignas(16) unsigned short Bs[BN * 32];
    const int t    = threadIdx.x;
    const int lane = t & 63;
    const int w    = t >> 6;
    const int bm   = SWAP ? blockIdx.x : blockIdx.y;
    const int bn   = SWAP ? blockIdx.y : blockIdx.x;
    const int m0   = bm * 128, n0 = bn * BN;
    const int wm   = (w >> 1) * 64, wn = (w & 1) * (NJ * 16);
    const int q    = lane >> 4, l15 = lane & 15;

    int mp[4];
#pragma unroll
    for (int r = 0; r < 4; r++) mp[r] = dmap[lane * 4 + r];

    const int srow = t >> 2;          // 0..63
    const int skk  = (t & 3) * 8;     // shorts: 0,8,16,24

    f32x4 acc[4][NJ];
#pragma unroll
    for (int i = 0; i < 4; i++)
#pragma unroll
        for (int j = 0; j < NJ; j++) acc[i][j] = (f32x4){0.f, 0.f, 0.f, 0.f};

    for (int k0 = 0; k0 < K; k0 += 32) {
        __syncthreads();   // waves done reading LDS from previous iter
        gl2lds16(&A[(size_t)(m0 +      srow) * K + k0 + skk], &As[(     srow) * 32 + skk]);
        gl2lds16(&A[(size_t)(m0 + 64 + srow) * K + k0 + skk], &As[(64 + srow) * 32 + skk]);
#pragma unroll
        for (int jb = 0; jb < NJ / 2; jb++)
            gl2lds16(&B[(size_t)(n0 + jb * 64 + srow) * K + k0 + skk],
                     &Bs[(jb * 64 + srow) * 32 + skk]);
        __syncthreads();   // vmcnt(0) drained before barrier -> tiles visible

        bf16x8 af[4], bfr[NJ];
#pragma unroll
        for (int i = 0; i < 4; i++)
            af[i] = *(const bf16x8*)&As[(wm + i * 16 + l15) * 32 + q * 8];
#pragma unroll
        for (int j = 0; j < NJ; j++)
            bfr[j] = *(const bf16x8*)&Bs[(wn + j * 16 + l15) * 32 + q * 8];
#pragma unroll
        for (int i = 0; i < 4; i++)
#pragma unroll
            for (int j = 0; j < NJ; j++)
                acc[i][j] = __builtin_amdgcn_mfma_f32_16x16x32_bf16(
                    af[i], bfr[j], acc[i][j], 0, 0, 0);
    }

    const int isbf = EPI ? *flagp : 0;
#pragma unroll
    for (int i = 0; i < 4; i++) {
#pragma unroll
        for (int r = 0; r < 4; r++) {
            const int mo = mp[r] & 15, no = mp[r] >> 4;
            const int m = m0 + wm + i * 16 + mo;
#pragma unroll
            for (int j = 0; j < NJ; j++) {
                const int n = n0 + wn + j * 16 + no;
                float v = acc[i][j][r];
                if (EPI == 1) {   // softplus(v + bias[n]), fast-math
                    v += ldF(bias, n, isbf);
                    v = fmaxf(v, 0.f) + __logf(1.f + __expf(-fabsf(v)));
                }
                C[(size_t)m * N + n] = v;
            }
        }
    }
}

// ---------------------------------------------------------------------------
// x_proj split-K: part[z][M][96] = xl[:, zKc:(z+1)Kc] @ x_proj_w[:, zKc:]^T
// ---------------------------------------------------------------------------
__launch_bounds__(256)
__global__ void xproj_splitk(const float* __restrict__ A,   // xl [4096,2048]
                             const float* __restrict__ B,   // x_proj_w [96,2048]
                             float* __restrict__ part)      // [XKS,4096,96]
{
    __shared__ alignas(16) float As[16][68];
    __shared__ alignas(16) float Bs[16][68];
    const int t  = threadIdx.x;
    const int m0 = blockIdx.y * 64, n0 = blockIdx.x * 64;
    const int koff = blockIdx.z * (D_INNER / XKS);           // 256-wide K chunk
    const int lr = t >> 2;
    const int lk = (t & 3) * 4;
    const int tm = t >> 4, tn = t & 15;

    float acc[4][4];
#pragma unroll
    for (int i = 0; i < 4; i++)
#pragma unroll
        for (int j = 0; j < 4; j++) acc[i][j] = 0.f;

    for (int k0 = koff; k0 < koff + D_INNER / XKS; k0 += 16) {
        float av[4], bv[4];
        {
            const int m = m0 + lr;
            float4 p = *(const float4*)&A[(size_t)m * D_INNER + k0 + lk];
            av[0] = p.x; av[1] = p.y; av[2] = p.z; av[3] = p.w;
        }
        {
            const int n = n0 + lr;
            if (n < XNC) {
                float4 p = *(const float4*)&B[(size_t)n * D_INNER + k0 + lk];
                bv[0] = p.x; bv[1] = p.y; bv[2] = p.z; bv[3] = p.w;
            } else { bv[0] = bv[1] = bv[2] = bv[3] = 0.f; }
        }
        __syncthreads();
#pragma unroll
        for (int i = 0; i < 4; i++) { As[lk + i][lr] = av[i]; Bs[lk + i][lr] = bv[i]; }
        __syncthreads();

#pragma unroll
        for (int kk = 0; kk < 16; kk++) {
            float4 a = *(const float4*)&As[kk][tm * 4];
            float4 b = *(const float4*)&Bs[kk][tn * 4];
            float aa[4] = { a.x, a.y, a.z, a.w };
            float bb[4] = { b.x, b.y, b.z, b.w };
#pragma unroll
            for (int i = 0; i < 4; i++)
#pragma unroll
                for (int j = 0; j < 4; j++) acc[i][j] = fmaf(aa[i], bb[j], acc[i][j]);
        }
    }

    float* out = part + (size_t)blockIdx.z * NTOK * XNC;
#pragma unroll
    for (int i = 0; i < 4; i++) {
        const int m = m0 + tm * 4 + i;
#pragma unroll
        for (int j = 0; j < 4; j++) {
            const int n = n0 + tn * 4 + j;
            if (n < XNC) out[(size_t)m * XNC + n] = acc[i][j];
        }
    }
}

__launch_bounds__(256)
__global__ void xproj_reduce(const float* __restrict__ part, float* __restrict__ xdbl)
{
    const int idx = blockIdx.x * 256 + threadIdx.x;          // NTOK*XNC
    float s = 0.f;
#pragma unroll
    for (int z = 0; z < XKS; z++) s += part[(size_t)z * NTOK * XNC + idx];
    xdbl[idx] = s;
}

// ---------------------------------------------------------------------------
// Depthwise causal conv1d (d_conv=4) + SiLU.
// ---------------------------------------------------------------------------
__launch_bounds__(256)
__global__ void conv_silu(const float* __restrict__ xz,
                          const void* __restrict__ conv_w,
                          const void* __restrict__ conv_b,
                          float* __restrict__ xl,
                          const int* __restrict__ flagp)
{
    const int isbf = *flagp;
    const int idx = blockIdx.x * 256 + threadIdx.x;
    const int d   = idx & (D_INNER - 1);
    const int tok = idx >> 11;
    const int l   = tok & (SEQLEN - 1);

    float acc = ldF(conv_b, d, isbf);
#pragma unroll
    for (int j = 0; j < 4; j++) {
        const int ll = l - 3 + j;
        if (ll >= 0)
            acc = fmaf(xz[(size_t)(tok - 3 + j) * (2 * D_INNER) + d],
                       ldF(conv_w, d * 4 + j, isbf), acc);
    }
    xl[idx] = acc / (1.f + expf(-acc));
}

// ---------------------------------------------------------------------------
// Scan phase 1: per-chunk local scan (h0=0) -> S[b,c,n,d], sumD[b,c,d].
// ---------------------------------------------------------------------------
__launch_bounds__(256)
__global__ void scan_chunk(const float* __restrict__ dlt,
                           const float* __restrict__ xl,
                           const float* __restrict__ xdbl,
                           const void* __restrict__ A_log,
                           float* __restrict__ S,
                           float* __restrict__ sumD,
                           const int* __restrict__ flagp)
{
    const int isbf = *flagp;
    const int t  = threadIdx.x;
    const int dg = blockIdx.x & 7;
    const int c  = (blockIdx.x >> 3) & (NCH - 1);
    const int b  = blockIdx.x >> 9;
    const int d  = dg * 256 + t;

    float An[16], h[16];
#pragma unroll
    for (int n = 0; n < 16; n++) {
        An[n] = -expf(ldF(A_log, d * 16 + n, isbf));
        h[n] = 0.f;
    }
    float sd = 0.f;
    const size_t r0 = (size_t)b * SEQLEN + c * LC;

    for (int i = 0; i < LC; i++) {
        const size_t r = r0 + i;
        const float dv = dlt[r * D_INNER + d];
        const float uv = xl [r * D_INNER + d];
        float Bv[16];
        ld16f(&xdbl[r * 96 + 64], Bv);
        const float du = dv * uv;
#pragma unroll
        for (int n = 0; n < 16; n++)
            h[n] = fmaf(__expf(dv * An[n]), h[n], du * Bv[n]);
        sd += dv;
    }

    const size_t base = (((size_t)b * NCH + c) * 16) * D_INNER + d;
#pragma unroll
    for (int n = 0; n < 16; n++) S[base + (size_t)n * D_INNER] = h[n];
    sumD[((size_t)b * NCH + c) * D_INNER + d] = sd;
}

// ---------------------------------------------------------------------------
// Scan phase 2: combine chunk states; S rewritten with chunk-START state H0.
// ---------------------------------------------------------------------------
__launch_bounds__(256)
__global__ void scan_combine(float* __restrict__ S,
                             const float* __restrict__ sumD,
                             const void* __restrict__ A_log,
                             const int* __restrict__ flagp)
{
    const int isbf = *flagp;
    const int g = blockIdx.x * 256 + threadIdx.x;
    const int d = g & (D_INNER - 1);
    const int n = (g >> 11) & 15;
    const int b = g >> 15;
    const float An = -expf(ldF(A_log, d * 16 + n, isbf));

    float hs = 0.f;
    for (int c = 0; c < NCH; c++) {
        const size_t idx = (((size_t)b * NCH + c) * 16 + n) * D_INNER + d;
        const float Sc = S[idx];
        const float sd = sumD[((size_t)b * NCH + c) * D_INNER + d];
        S[idx] = hs;
        hs = fmaf(__expf(An * sd), hs, Sc);
    }
}

// ---------------------------------------------------------------------------
// Scan phase 3: seeded re-scan; y = sum_n h*C; D-skip + silu(z) gate -> bf16 yg.
// ---------------------------------------------------------------------------
__launch_bounds__(256)
__global__ void scan_apply(const float* __restrict__ dlt,
                           const float* __restrict__ xl,
                           const float* __restrict__ xdbl,
                           const float* __restrict__ xz,
                           const void* __restrict__ A_log,
                           const void* __restrict__ Dp,
                           const float* __restrict__ S,   // holds H0
                           unsigned short* __restrict__ yg,
                           const int* __restrict__ flagp)
{
    const int isbf = *flagp;
    const int t  = threadIdx.x;
    const int dg = blockIdx.x & 7;
    const int c  = (blockIdx.x >> 3) & (NCH - 1);
    const int b  = blockIdx.x >> 9;
    const int d  = dg * 256 + t;

    float An[16], h[16];
    const size_t base = (((size_t)b * NCH + c) * 16) * D_INNER + d;
#pragma unroll
    for (int n = 0; n < 16; n++) {
        An[n] = -expf(ldF(A_log, d * 16 + n, isbf));
        h[n] = S[base + (size_t)n * D_INNER];
    }
    const float Dd = ldF(Dp, d, isbf);
    const size_t r0 = (size_t)b * SEQLEN + c * LC;

    for (int i = 0; i < LC; i++) {
        const size_t r = r0 + i;
        const float dv = dlt[r * D_INNER + d];
        const float uv = xl [r * D_INNER + d];
        const float zv = xz [r * (2 * D_INNER) + D_INNER + d];
        float Bv[16], Cv[16];
        ld16f(&xdbl[r * 96 + 64], Bv);
        ld16f(&xdbl[r * 96 + 80], Cv);
        const float du = dv * uv;
        float s[16];
#pragma unroll
        for (int n = 0; n < 16; n++) {
            h[n] = fmaf(__expf(dv * An[n]), h[n], du * Bv[n]);
            s[n] = h[n] * Cv[n];
        }
#pragma unroll
        for (int n = 0; n < 8; n++) s[n] += s[n + 8];
#pragma unroll
        for (int n = 0; n < 4; n++) s[n] += s[n + 4];
        s[0] += s[2]; s[1] += s[3];
        const float yv = s[0] + s[1] + uv * Dd;
        yg[r * D_INNER + d] = f2bf(yv * (zv / (1.f + expf(-zv))));
    }
}

// ---------------------------------------------------------------------------
extern "C" void kernel_launch(void* const* d_in, const int* in_sizes, int n_in,
                              void* d_out, int out_size, void* d_ws, size_t ws_size,
                              hipStream_t stream)
{
    const void* hidden     = d_in[0]; // f32
    const void* in_proj_w  = d_in[1];
    const void* conv_w     = d_in[2];
    const void* conv_b     = d_in[3];
    const void* x_proj_w   = d_in[4];
    const void* dt_proj_w  = d_in[5];
    const void* dt_proj_b  = d_in[6];
    const void* A_log      = d_in[7];
    const void* Dp         = d_in[8];
    const void* out_proj_w = d_in[9];

    char* ws = (char*)d_ws;
    float*          xz   = (float*)(ws);                        // [4096,4096]  64 MB
    float*          xl   = (float*)(ws + 67108864ull);          // [4096,2048]  32 MB
    float*          xdbl = (float*)(ws + 100663296ull);         // [4096,96]   1.5 MB
    float*          dlt  = (float*)(ws + 102236160ull);         // [4096,2048]  32 MB (step 4)
    unsigned short* yg   = (unsigned short*)(ws + 135790592ull);// [4096,2048] bf16 16 MB
    unsigned short* opwB = (unsigned short*)(ws + 152567808ull);// out_proj_w bf16 4 MB
    unsigned short* xdt  = (unsigned short*)(ws + 156762112ull);// [4096,64] bf16 512 KB (hole)
    unsigned short* dtwB = (unsigned short*)(ws + 157286400ull);// [2048,64] bf16 256 KB (hole)
    int*            flag = (int*)  (ws + 169345024ull);
    float*          S    = (float*)(ws + 169345280ull);         // 16 MB
    float*          sumD = (float*)(ws + 186122496ull);         // 1 MB
    int*            dmap = (int*)  (ws + 187171072ull);         // 256 B probe LUT
    // transient occupants of the dlt region (dead before dt-GEMM writes dlt):
    unsigned short* hidB  = (unsigned short*)(ws + 102236160ull);              // 8 MB
    unsigned short* ipwB  = (unsigned short*)(ws + 102236160ull + 8388608ull); // 8 MB
    float*          xpart = (float*)(ws + 102236160ull);        // [8,4096,96] 12.6 MB

    dim3 blk(256);

    sniff<<<dim3(1), dim3(64), 0, stream>>>((const unsigned int*)Dp, (int*)flag);
    mfma_probe<<<dim3(1), dim3(64), 0, stream>>>(dmap);

    // 0) f32 -> bf16 copies for MFMA operands
    cvt_bf16<<<dim3(NTOK * D_MODEL / 256), blk, 0, stream>>>(hidden, hidB, NTOK * D_MODEL, flag);
    cvt_bf16<<<dim3(2 * D_INNER * D_MODEL / 256), blk, 0, stream>>>(in_proj_w, ipwB, 2 * D_INNER * D_MODEL, flag);
    cvt_bf16<<<dim3(D_MODEL * D_INNER / 256), blk, 0, stream>>>(out_proj_w, opwB, D_MODEL * D_INNER, flag);
    cvt_bf16<<<dim3(D_INNER * DT_RANK / 256), blk, 0, stream>>>(dt_proj_w, dtwB, D_INNER * DT_RANK, flag);

    // 1) xz = hidden @ in_proj_w^T   [4096,4096]  (bf16 MFMA, BN=128)
    gemm_mfma_bt<0, 4, 0><<<dim3(32, 32), blk, 0, stream>>>(
        hidB, ipwB, xz, NTOK, 2 * D_INNER, D_MODEL, dmap, nullptr, flag);

    // 2) xl = silu(causal_conv1d(x) + conv_b)
    conv_silu<<<dim3(NTOK * D_INNER / 256), blk, 0, stream>>>(xz, conv_w, conv_b, xl, flag);

    // 3) xdbl = xl @ x_proj_w^T  via split-K
    xproj_splitk<<<dim3(2, 64, XKS), blk, 0, stream>>>(
        xl, (const float*)x_proj_w, xpart);
    xproj_reduce<<<dim3(NTOK * XNC / 256), blk, 0, stream>>>(xpart, xdbl);

    // 4) delta = softplus(dt @ dt_proj_w^T + dt_proj_b)  via bf16 MFMA (K=64)
    pack_xdt<<<dim3(NTOK * DT_RANK / 256), blk, 0, stream>>>(xdbl, xdt);
    gemm_mfma_bt<1, 4, 0><<<dim3(16, 32), blk, 0, stream>>>(
        xdt, dtwB, dlt, NTOK, D_INNER, DT_RANK, dmap, dt_proj_b, flag);

    // 5) chunked parallel scan + D-skip + silu(z) gate -> yg (bf16)
    scan_chunk<<<dim3(BATCH * NCH * (D_INNER / 256)), blk, 0, stream>>>(
        dlt, xl, xdbl, A_log, S, sumD, flag);
    scan_combine<<<dim3(BATCH * 16 * D_INNER / 256), blk, 0, stream>>>(
        S, sumD, A_log, flag);
    scan_apply<<<dim3(BATCH * NCH * (D_INNER / 256)), blk, 0, stream>>>(
        dlt, xl, xdbl, xz, A_log, Dp, S, yg, flag);

    // 6) out = yg @ out_proj_w^T -> f32 d_out
    //    BN=64 (2 blocks/CU) + M-major grid (A-tiles pinned per-XCD in L2)
    gemm_mfma_bt<0, 2, 1><<<dim3(32, 16), blk, 0, stream>>>(
        yg, opwB, (float*)d_out, NTOK, D_MODEL, D_INNER, dmap, nullptr, flag);
}